// Round 10
// baseline (346.510 us; speedup 1.0000x reference)
//
#include <hip/hip_runtime.h>
#include <hip/hip_bf16.h>

// GAT-GAE forward: 2x GATConv + normalize + MLP decoder. fp32 I/O, int32 edges.
// Round 19: deg blocks moved to the FRONT of the merged xprep_deg grid.
// R18's counters showed the merged kernel at 67us with 39MB writes (~25MB
// amplification): deg's 8-bin XCD trick requires bin = blockIdx&7 under
// round-robin dispatch FROM BLOCK 0; placing deg at offset nblk4 randomized
// the bin->XCD mapping and rowptr atomic lines ping-ponged across the 8
// non-coherent L2s (same disease R12 cured in fill_k). Partition order is
// the only change vs the verified R18: blocks [0,bgrid) = deg, rest = xprep.
//
// Workspace (bytes): W1f 64K | W2f 32K | u_s 2K | u_d 2K |
//   xagg u16[N*512] | xb u16[N*128] | h2b u16[N*64] |
//   a_s1 f32[4N] | a_d1 f32[4N] | a_s2 f32[N] | a_d2 f32[N] |
//   rowptr int[N+1] | cursor int[N] | col int[Etot] | psum int[256]

#define IN_DIM   128
#define C1       256   // HEADS*HID
#define HEADS    4
#define HID      64
#define OUT_DIM  64

typedef __attribute__((ext_vector_type(8))) short short8;
typedef __attribute__((ext_vector_type(4))) float f32x4;
typedef __attribute__((ext_vector_type(2))) float f32x2;

__device__ __forceinline__ float lrelu(float x) { return x > 0.f ? x : 0.2f * x; }
__device__ __forceinline__ float elu1(float x)  { return x > 0.f ? x : (__expf(x) - 1.f); }
__device__ __forceinline__ float expc(float x)  { return __expf(fminf(x, 60.f)); }
__device__ __forceinline__ float bfu(unsigned int u) {
    union { unsigned int i; float f; } c; c.i = u << 16; return c.f;
}
__device__ __forceinline__ unsigned short pk(float f) {
    union { float f; unsigned int i; } c; c.f = f;
    return (unsigned short)((c.i + 0x7fffu + ((c.i >> 16) & 1u)) >> 16);
}
// acc.{lo,hi} += x.{lo,hi} * wpair.lo   (both result halves read src1 LO)
__device__ __forceinline__ void pkfma_lo(f32x2& acc, const f32x2 x, const f32x2 wp) {
    asm("v_pk_fma_f32 %0, %1, %2, %0 op_sel_hi:[1,0,1]"
        : "+v"(acc) : "v"(x), "v"(wp));
}
// acc.{lo,hi} += x.{lo,hi} * wpair.hi   (both result halves read src1 HI)
__device__ __forceinline__ void pkfma_hi(f32x2& acc, const f32x2 x, const f32x2 wp) {
    asm("v_pk_fma_f32 %0, %1, %2, %0 op_sel:[0,1,0] op_sel_hi:[1,1,1]"
        : "+v"(acc) : "v"(x), "v"(wp));
}
// unpack bf16 pair (lo,hi of u32) into packed f32x2
__device__ __forceinline__ f32x2 bf2up(unsigned int u) {
    union { unsigned int i[2]; f32x2 f; } c;
    c.i[0] = u << 16;
    c.i[1] = u & 0xffff0000u;
    return c.f;
}

// ======== weight prepack (merged): B-fragment order for 16x16x32 bf16 =======
// Blocks 0..15: W1 [128][256] fp32 -> W1f[((nt*4+kc)*64 + lane)*8 + j] =
//   bf16(W1[(kc*32 + (lane>>4)*8 + j)*256 + nt*16 + (lane&15)])
// Block 16: u_s[h*128+k] = sum_c W1[k][h*64+c]*att_src1[h][c]; u_d likewise.
// Blocks 17..24: W2 [256][64] fp32 -> W2f[((nt*8+kc)*64 + lane)*8 + j]
__global__ __launch_bounds__(256) void w1f_k(const float* __restrict__ W1,
                                             const float* __restrict__ W2,
                                             const float* __restrict__ as1,
                                             const float* __restrict__ ad1,
                                             unsigned short* __restrict__ W1f,
                                             unsigned short* __restrict__ W2f,
                                             float* __restrict__ u_s,
                                             float* __restrict__ u_d)
{
    const int b = blockIdx.x;
    if (b == 16) {
        for (int idx = threadIdx.x; idx < 512; idx += 256) {
            const int h = idx >> 7, k = idx & 127;
            float ss = 0.f, dd = 0.f;
            #pragma unroll 4
            for (int c = 0; c < 64; ++c) {
                const float wv = W1[k * 256 + h * 64 + c];
                ss += wv * as1[h * 64 + c];
                dd += wv * ad1[h * 64 + c];
            }
            u_s[idx] = ss;
            u_d[idx] = dd;
        }
        return;
    }
    if (b >= 17) {   // W2f pack
        const int idx = (b - 17) * 256 + threadIdx.x;   // 2048 lane-entries
        if (idx >= 32 * 64) return;
        const int lane = idx & 63, e = idx >> 6;
        const int nt = e >> 3, kc = e & 7, q = lane >> 4, c = lane & 15;
        unsigned short tmp[8];
        #pragma unroll
        for (int j = 0; j < 8; ++j)
            tmp[j] = pk(W2[(kc * 32 + q * 8 + j) * 64 + nt * 16 + c]);
        ushort4* dst = (ushort4*)(W2f + (size_t)idx * 8);
        dst[0] = make_ushort4(tmp[0], tmp[1], tmp[2], tmp[3]);
        dst[1] = make_ushort4(tmp[4], tmp[5], tmp[6], tmp[7]);
        return;
    }
    const int idx = b * 256 + threadIdx.x;   // 4096 lane-entries
    if (idx >= 64 * 64) return;
    const int lane = idx & 63, e = idx >> 6;
    const int nt = e >> 2, kc = e & 3, q = lane >> 4, c = lane & 15;
    unsigned short tmp[8];
    #pragma unroll
    for (int j = 0; j < 8; ++j)
        tmp[j] = pk(W1[(kc * 32 + q * 8 + j) * 256 + nt * 16 + c]);
    ushort4* dst = (ushort4*)(W1f + (size_t)idx * 8);
    dst[0] = make_ushort4(tmp[0], tmp[1], tmp[2], tmp[3]);
    dst[1] = make_ushort4(tmp[4], tmp[5], tmp[6], tmp[7]);
}

// ==== deg (blocks < bgrid, FIRST for clean XCD round-robin) + xprep (rest) ==
// deg: 8-binned degree count, bin = blockIdx&7 ~ XCD (dispatch from block 0).
// xprep: 1 wave/node, lane l owns ch 2l,2l+1; a_s1[n,h] = x[n]·u_s[h].
__global__ __launch_bounds__(256) void xprep_deg_k(
    const float* __restrict__ x, const float* __restrict__ u_s,
    const float* __restrict__ u_d, unsigned short* __restrict__ xb,
    float* __restrict__ a_s1, float* __restrict__ a_d1, int N,
    const int* __restrict__ ei, int E, int Etot, int* __restrict__ rowptr,
    int bgrid, int nchunk)
{
    if (blockIdx.x < bgrid) {            // ---- deg part (front of grid) ----
        const int bb = blockIdx.x;
        const int bin = bb & 7;
        const int chunk = bb >> 3;
        const int per = (Etot + nchunk - 1) / nchunk;
        const int e0 = chunk * per, e1 = min(e0 + per, Etot);
        const int lo = (int)(((long long)N * bin) >> 3);
        const int hi = (int)(((long long)N * (bin + 1)) >> 3);
        for (int e = e0 + threadIdx.x; e < e1; e += 256) {
            const int d = (e < E) ? ei[E + e] : e - E;
            if (d >= lo && d < hi) atomicAdd(&rowptr[1 + d], 1);
        }
        return;
    }
    // ---- xprep part ----
    __shared__ float us[512], ud[512];
    const int t = threadIdx.x;
    for (int i = t; i < 512; i += 256) { us[i] = u_s[i]; ud[i] = u_d[i]; }
    __syncthreads();
    const int w = t >> 6, l = t & 63;
    const int n = (blockIdx.x - bgrid) * 4 + w;
    if (n >= N) return;
    const float2 xv = *(const float2*)&x[(size_t)n * IN_DIM + 2 * l];
    const unsigned int p2 =
        (unsigned int)pk(xv.x) | ((unsigned int)pk(xv.y) << 16);
    *(unsigned int*)&xb[(size_t)n * IN_DIM + 2 * l] = p2;
    #pragma unroll
    for (int h = 0; h < 4; ++h) {
        float ps = xv.x * us[h * 128 + 2 * l] + xv.y * us[h * 128 + 2 * l + 1];
        float pd = xv.x * ud[h * 128 + 2 * l] + xv.y * ud[h * 128 + 2 * l + 1];
        #pragma unroll
        for (int off = 1; off < 64; off <<= 1) {
            ps += __shfl_xor(ps, off, 64);
            pd += __shfl_xor(pd, off, 64);
        }
        if (l == 0) {
            a_s1[n * 4 + h] = ps;
            a_d1[n * 4 + h] = pd;
        }
    }
}

__device__ __forceinline__ int blk_incl_scan(int v, int t) {
    __shared__ int wsum[4];
    const int lane = t & 63, wid = t >> 6;
    int s = v;
    #pragma unroll
    for (int off = 1; off < 64; off <<= 1) {
        const int u = __shfl_up(s, off, 64);
        if (lane >= off) s += u;
    }
    if (lane == 63) wsum[wid] = s;
    __syncthreads();
    int add = 0;
    #pragma unroll
    for (int k = 0; k < 4; ++k) if (k < wid) add += wsum[k];
    __syncthreads();
    return s + add;
}

__global__ __launch_bounds__(256) void scanA_k(const int* __restrict__ rowptr,
                                               int* __restrict__ psum, int N)
{
    const int t = threadIdx.x;
    const int i = blockIdx.x * 256 + t;
    int v = (i < N) ? rowptr[1 + i] : 0;
    #pragma unroll
    for (int off = 1; off < 64; off <<= 1) v += __shfl_xor(v, off, 64);
    __shared__ int ws[4];
    if ((t & 63) == 0) ws[t >> 6] = v;
    __syncthreads();
    if (t == 0) psum[blockIdx.x] = ws[0] + ws[1] + ws[2] + ws[3];
}

// scanC with inline base computation: base = sum(psum[0..blockIdx.x)).
// psum holds UNSCANNED per-chunk totals from scanA; SC <= 256.
__global__ __launch_bounds__(256) void scanC_k(int* __restrict__ rowptr,
                                               int* __restrict__ cursor,
                                               const int* __restrict__ psum,
                                               int N, int SC)
{
    const int t = threadIdx.x;
    int s = (t < SC && t < (int)blockIdx.x) ? psum[t] : 0;
    #pragma unroll
    for (int off = 1; off < 64; off <<= 1) s += __shfl_xor(s, off, 64);
    __shared__ int bsum[4];
    if ((t & 63) == 0) bsum[t >> 6] = s;
    __syncthreads();
    const int base = bsum[0] + bsum[1] + bsum[2] + bsum[3];
    __syncthreads();                      // bsum reuse safety vs blk_incl_scan
    const int i = blockIdx.x * 256 + t;
    const int v = (i < N) ? rowptr[1 + i] : 0;
    const int inc = blk_incl_scan(v, t);
    if (i < N) {
        rowptr[1 + i] = base + inc;
        cursor[i]     = base + inc - v;
    }
}

// Binned fill: bin's col region stays in the local XCD L2 and accumulates
// FULL dirty lines before writeback (R12: 55MB -> ~3.4MB HBM writes).
__global__ __launch_bounds__(256) void fill_k(const int* __restrict__ ei, int E,
                                              int Etot, int* __restrict__ cursor,
                                              int* __restrict__ col, int N)
{
    const int bin = blockIdx.x & 7;
    const int chunk = blockIdx.x >> 3, nchunk = gridDim.x >> 3;
    const int per = (Etot + nchunk - 1) / nchunk;
    const int e0 = chunk * per, e1 = min(e0 + per, Etot);
    const int lo = (int)(((long long)N * bin) >> 3);
    const int hi = (int)(((long long)N * (bin + 1)) >> 3);
    for (int e = e0 + threadIdx.x; e < e1; e += 256) {
        const int d = (e < E) ? ei[E + e] : e - E;
        if (d >= lo && d < hi) {
            const int s = (e < E) ? ei[e] : d;
            const int pos = atomicAdd(&cursor[d], 1);
            col[pos] = s;
        }
    }
}

// ====== Layer-1 aggregate over x: xagg[n,h,:] = (sum_e w_e^h x[src]) / sum w ==
// 1 wave/node; lane l owns channels (2l,2l+1) for all 4 heads (packed f32x2
// per head, v_pk_fma_f32 with op_sel half-select). Per 64-edge chunk: lane l
// stages edge (t0+l)'s {scol, float4 weights} into per-wave LDS; consume loop
// reads them via uniform ds_read (broadcast). 8 gathers in flight (verified
// optimum: 16-deep raised VGPR to 64 and cost 22% -- R16).
__global__ __launch_bounds__(256) void agg1x_k(
    const int* __restrict__ rowptr, const int* __restrict__ col,
    const float* __restrict__ a_s1, const float* __restrict__ a_d1,
    const unsigned short* __restrict__ xb, unsigned short* __restrict__ xagg,
    int N)
{
    __shared__ int    scolS[4][64];
    __shared__ float4 w4S[4][64];
    const int t = threadIdx.x, w = t >> 6, l = t & 63;
    const int n = blockIdx.x * 4 + w;
    if (n >= N) return;
    const int beg = rowptr[n], end = rowptr[n + 1];
    const float4 dv = *(const float4*)&a_d1[n * 4];
    float4 ws = {0.f, 0.f, 0.f, 0.f};
    f32x2 acc[4] = {{0.f,0.f},{0.f,0.f},{0.f,0.f},{0.f,0.f}};
    const unsigned short* xbl = xb + 2 * l;
    for (int t0 = beg; t0 < end; t0 += 64) {
        const int m = min(64, end - t0);
        const int p = t0 + l;
        int sc = 0;
        float4 wv = {0.f, 0.f, 0.f, 0.f};
        if (p < end) {
            sc = col[p];
            const float4 av = *(const float4*)&a_s1[sc * 4];
            wv.x = expc(lrelu(av.x + dv.x));
            wv.y = expc(lrelu(av.y + dv.y));
            wv.z = expc(lrelu(av.z + dv.z));
            wv.w = expc(lrelu(av.w + dv.w));
            ws.x += wv.x; ws.y += wv.y; ws.z += wv.z; ws.w += wv.w;
        }
        scolS[w][l] = sc;
        w4S[w][l]   = wv;
        __threadfence_block();           // within-wave LDS write->read order
        for (int j0 = 0; j0 < m; j0 += 8) {
            const int4 s0 = *(const int4*)&scolS[w][j0];
            const int4 s1 = *(const int4*)&scolS[w][j0 + 4];
            const int su[8] = {s0.x, s0.y, s0.z, s0.w, s1.x, s1.y, s1.z, s1.w};
            unsigned int hv[8];
            #pragma unroll
            for (int u = 0; u < 8; ++u)   // 8 gathers in flight
                hv[u] = *(const unsigned int*)(xbl + (size_t)su[u] * IN_DIM);
            #pragma unroll
            for (int u = 0; u < 8; ++u) {
                const float* wb = (const float*)&w4S[w][j0 + u];
                const f32x2 wp01 = *(const f32x2*)(wb);      // {w0,w1}
                const f32x2 wp23 = *(const f32x2*)(wb + 2);  // {w2,w3}
                const f32x2 xv = bf2up(hv[u]);
                pkfma_lo(acc[0], xv, wp01);
                pkfma_hi(acc[1], xv, wp01);
                pkfma_lo(acc[2], xv, wp23);
                pkfma_hi(acc[3], xv, wp23);
            }
        }
    }
    #pragma unroll
    for (int off = 1; off < 64; off <<= 1) {
        ws.x += __shfl_xor(ws.x, off, 64);
        ws.y += __shfl_xor(ws.y, off, 64);
        ws.z += __shfl_xor(ws.z, off, 64);
        ws.w += __shfl_xor(ws.w, off, 64);
    }
    const float i0 = 1.f / (ws.x + 1e-16f), i1 = 1.f / (ws.y + 1e-16f);
    const float i2 = 1.f / (ws.z + 1e-16f), i3 = 1.f / (ws.w + 1e-16f);
    unsigned short* out = xagg + (size_t)n * 512 + 2 * l;
    *(unsigned int*)(out)       = (unsigned int)pk(acc[0][0] * i0) |
                                  ((unsigned int)pk(acc[0][1] * i0) << 16);
    *(unsigned int*)(out + 128) = (unsigned int)pk(acc[1][0] * i1) |
                                  ((unsigned int)pk(acc[1][1] * i1) << 16);
    *(unsigned int*)(out + 256) = (unsigned int)pk(acc[2][0] * i2) |
                                  ((unsigned int)pk(acc[2][1] * i2) << 16);
    *(unsigned int*)(out + 384) = (unsigned int)pk(acc[3][0] * i3) |
                                  ((unsigned int)pk(acc[3][1] * i3) << 16);
}

// ====== Fused layer-1 + layer-2 GEMM (MFMA), LDS handoff (no hxb) ==========
// Phase 1 (old gemm1b): hx = elu(xagg @ W1 + b1) block-diagonal; epilogue
// lands in lds stride 264 -- the exact layout old gemm2 staged from global.
// Phase 2 (old gemm2): h2 = hx @ W2 + logits, reading lds directly. Each
// wave's phase-2 A-rows (16w+c) are the rows the same wave wrote in phase 1.
__global__ __launch_bounds__(256) void gemm12_k(
    const unsigned short* __restrict__ xagg, const unsigned short* __restrict__ W1f,
    const float* __restrict__ b1, const unsigned short* __restrict__ W2f,
    const float* __restrict__ as2, const float* __restrict__ ad2,
    unsigned short* __restrict__ h2b, float* __restrict__ a_s2,
    float* __restrict__ a_d2, int N)
{
    __shared__ short lds[64 * 264];
    const int t = threadIdx.x, w = t >> 6, l = t & 63;
    const int q = l >> 4, c = l & 15;
    const int n0 = blockIdx.x * 64;
    const int arow = 16 * w + c;
    // ---------------- phase 1: block-diag W1 ----------------
    f32x4 acc[16];
    #pragma unroll
    for (int nt = 0; nt < 16; ++nt) acc[nt] = (f32x4){0.f, 0.f, 0.f, 0.f};
    #pragma unroll
    for (int half = 0; half < 2; ++half) {
        if (half) __syncthreads();           // protect LDS reuse
        for (int i = t; i < 64 * 32; i += 256) {
            const int r = i >> 5, ch = (i & 31) * 8;
            const int rn = min(n0 + r, N - 1);
            *(short8*)&lds[r * 264 + ch] =
                *(const short8*)&xagg[(size_t)rn * 512 + half * 256 + ch];
        }
        __syncthreads();
        #pragma unroll
        for (int hh = 0; hh < 2; ++hh) {
            const int h = half * 2 + hh;
            short8 afr[4];
            #pragma unroll
            for (int kc = 0; kc < 4; ++kc)
                afr[kc] = *(const short8*)&lds[arow * 264 + hh * 128 + kc * 32 + q * 8];
            #pragma unroll
            for (int nt = 0; nt < 4; ++nt) {
                #pragma unroll
                for (int kc = 0; kc < 4; ++kc) {
                    const short8 bfr = *(const short8*)(W1f +
                        ((size_t)((h * 4 + nt) * 4 + kc) * 64 + l) * 8);
                    acc[h * 4 + nt] = __builtin_amdgcn_mfma_f32_16x16x32_bf16(
                        afr[kc], bfr, acc[h * 4 + nt], 0, 0, 0);
                }
            }
        }
    }
    __syncthreads();
    #pragma unroll
    for (int nt = 0; nt < 16; ++nt)
        #pragma unroll
        for (int r = 0; r < 4; ++r) {
            const float v = elu1(acc[nt][r] + b1[nt * 16 + c]);
            lds[(16 * w + q * 4 + r) * 264 + nt * 16 + c] = (short)pk(v);
        }
    __syncthreads();
    // ---------------- phase 2: W2 + logits ----------------
    short8 afr2[8];
    #pragma unroll
    for (int kc = 0; kc < 8; ++kc)
        afr2[kc] = *(const short8*)&lds[arow * 264 + kc * 32 + q * 8];
    f32x4 acc2[4];
    #pragma unroll
    for (int nt = 0; nt < 4; ++nt) acc2[nt] = (f32x4){0.f, 0.f, 0.f, 0.f};
    #pragma unroll
    for (int nt = 0; nt < 4; ++nt) {
        #pragma unroll
        for (int kc = 0; kc < 8; ++kc) {
            const short8 bfr =
                *(const short8*)(W2f + ((size_t)(nt * 8 + kc) * 64 + l) * 8);
            acc2[nt] = __builtin_amdgcn_mfma_f32_16x16x32_bf16(afr2[kc], bfr,
                                                               acc2[nt], 0, 0, 0);
        }
    }
    {
        float vsr[4] = {0.f, 0.f, 0.f, 0.f}, vdr[4] = {0.f, 0.f, 0.f, 0.f};
        #pragma unroll
        for (int nt = 0; nt < 4; ++nt) {
            const float sa = as2[nt * 16 + c], da = ad2[nt * 16 + c];
            #pragma unroll
            for (int r = 0; r < 4; ++r) {
                vsr[r] += acc2[nt][r] * sa;
                vdr[r] += acc2[nt][r] * da;
            }
        }
        #pragma unroll
        for (int r = 0; r < 4; ++r) {
            #pragma unroll
            for (int off = 1; off < 16; off <<= 1) {
                vsr[r] += __shfl_xor(vsr[r], off, 64);
                vdr[r] += __shfl_xor(vdr[r], off, 64);
            }
            const int node = n0 + 16 * w + q * 4 + r;
            if (c == 0 && node < N) {
                a_s2[node] = vsr[r];
                a_d2[node] = vdr[r];
            }
        }
    }
    __syncthreads();
    #pragma unroll
    for (int nt = 0; nt < 4; ++nt)
        #pragma unroll
        for (int r = 0; r < 4; ++r)
            lds[(16 * w + q * 4 + r) * 72 + nt * 16 + c] = (short)pk(acc2[nt][r]);
    __syncthreads();
    for (int i = t; i < 64 * 8; i += 256) {
        const int r = i >> 3, ch = (i & 7) * 8;
        const int node = n0 + r;
        if (node < N)
            *(short8*)&h2b[(size_t)node * OUT_DIM + ch] =
                *(const short8*)&lds[r * 72 + ch];
    }
}

// ====== Layer-2 aggregate: 1 wave/node, lane = 2 ch; LDS-staged weights =====
// Staged int2{scol,w} IS the 64-bit pair for pk_fma (w in hi half).
__global__ __launch_bounds__(256) void agg2_k(
    const int* __restrict__ rowptr, const int* __restrict__ col,
    const float* __restrict__ a_s2, const float* __restrict__ a_d2,
    const unsigned short* __restrict__ h2b, const float* __restrict__ b2,
    float* __restrict__ zout, int N)
{
    __shared__ int2 swS[4][64];
    const int t = threadIdx.x, w = t >> 6, l = t & 63;
    const int n = blockIdx.x * 4 + w;
    if (n >= N) return;
    const int beg = rowptr[n], end = rowptr[n + 1];
    const float dn = a_d2[n];
    const int half = l >> 5, c2 = l & 31;     // lane owns ch 2*c2, 2*c2+1
    f32x2 acc = {0.f, 0.f};
    float wsum = 0.f;
    const unsigned short* h2l = h2b + 2 * c2;
    for (int t0 = beg; t0 < end; t0 += 64) {
        const int m = min(64, end - t0);
        const int p = t0 + l;
        int sc = 0; float wv = 0.f;
        if (p < end) {
            sc = col[p];
            wv = expc(lrelu(a_s2[sc] + dn));
            wsum += wv;
        }
        swS[w][l] = make_int2(sc, __float_as_int(wv));
        __threadfence_block();           // within-wave LDS write->read order
        const int pairs = (m + 1) >> 1;
        for (int j0 = 0; j0 < pairs; j0 += 8) {
            int2 sv[8];
            #pragma unroll
            for (int u = 0; u < 8; ++u)
                sv[u] = swS[w][2 * (j0 + u) + half];
            unsigned int hv[8];
            #pragma unroll
            for (int u = 0; u < 8; ++u)
                hv[u] = *(const unsigned int*)(h2l + (size_t)sv[u].x * OUT_DIM);
            #pragma unroll
            for (int u = 0; u < 8; ++u) {
                union { int2 i; f32x2 f; } cv; cv.i = sv[u];
                pkfma_hi(acc, bf2up(hv[u]), cv.f);
            }
        }
    }
    float a0 = acc[0], a1 = acc[1];
    a0 += __shfl_xor(a0, 32, 64);
    a1 += __shfl_xor(a1, 32, 64);
    #pragma unroll
    for (int off = 1; off < 64; off <<= 1) wsum += __shfl_xor(wsum, off, 64);
    const float inv = 1.f / (wsum + 1e-16f);
    float z0 = a0 * inv + b2[2 * c2];
    float z1 = a1 * inv + b2[2 * c2 + 1];
    float sq = z0 * z0 + z1 * z1;
    #pragma unroll
    for (int off = 1; off < 32; off <<= 1) sq += __shfl_xor(sq, off, 64);
    const float rn = 1.f / fmaxf(sqrtf(sq), 1e-12f);
    if (l < 32) {
        float2 o; o.x = z0 * rn; o.y = z1 * rn;
        *(float2*)&zout[(size_t)n * OUT_DIM + 2 * c2] = o;
    }
}

// ================= Decoder: x_hat = elu(z@dW1+db1)@dW2+db2 =================
__global__ __launch_bounds__(256) void dec_k(
    const float* __restrict__ z,
    const float* __restrict__ dW1, const float* __restrict__ db1,
    const float* __restrict__ dW2, const float* __restrict__ db2,
    float* __restrict__ xhat, int N)
{
    __shared__ float zs[32 * 64];
    __shared__ float ts[32 * 64];
    const int t = threadIdx.x;
    const int n0 = blockIdx.x * 32;
    for (int i = t; i < 32 * 64; i += 256) {
        const int nb_l = i >> 6, k = i & 63;
        const int n = min(n0 + nb_l, N - 1);
        zs[(nb_l >> 3) * 512 + k * 8 + (nb_l & 7)] = z[(size_t)n * OUT_DIM + k];
    }
    __syncthreads();
    const int w = t >> 6, l = t & 63;
    const float* zw = zs + w * 512;
    float* tw = ts + w * 512;
    float acc[8] = {0.f, 0.f, 0.f, 0.f, 0.f, 0.f, 0.f, 0.f};
    #pragma unroll 4
    for (int k = 0; k < 64; ++k) {
        const float wv = dW1[k * HID + l];
        const float4 xa = *(const float4*)&zw[k * 8];
        const float4 xb = *(const float4*)&zw[k * 8 + 4];
        acc[0] += xa.x * wv; acc[1] += xa.y * wv;
        acc[2] += xa.z * wv; acc[3] += xa.w * wv;
        acc[4] += xb.x * wv; acc[5] += xb.y * wv;
        acc[6] += xb.z * wv; acc[7] += xb.w * wv;
    }
    const float bb = db1[l];
    #pragma unroll
    for (int nb = 0; nb < 8; ++nb) tw[l * 8 + nb] = elu1(acc[nb] + bb);
    __syncthreads();
    float a0[8] = {0.f, 0.f, 0.f, 0.f, 0.f, 0.f, 0.f, 0.f};
    float a1[8] = {0.f, 0.f, 0.f, 0.f, 0.f, 0.f, 0.f, 0.f};
    #pragma unroll 2
    for (int k = 0; k < 64; ++k) {
        const float w0 = dW2[k * IN_DIM + l];
        const float w1 = dW2[k * IN_DIM + 64 + l];
        const float4 xa = *(const float4*)&tw[k * 8];
        const float4 xb = *(const float4*)&tw[k * 8 + 4];
        const float xv[8] = {xa.x, xa.y, xa.z, xa.w, xb.x, xb.y, xb.z, xb.w};
        #pragma unroll
        for (int nb = 0; nb < 8; ++nb) {
            a0[nb] += xv[nb] * w0;
            a1[nb] += xv[nb] * w1;
        }
    }
    const float bb0 = db2[l], bb1 = db2[64 + l];
    #pragma unroll
    for (int nb = 0; nb < 8; ++nb) {
        const int n = n0 + w * 8 + nb;
        if (n >= N) break;
        xhat[(size_t)n * IN_DIM + l]      = a0[nb] + bb0;
        xhat[(size_t)n * IN_DIM + 64 + l] = a1[nb] + bb1;
    }
}

extern "C" void kernel_launch(void* const* d_in, const int* in_sizes, int n_in,
                              void* d_out, int out_size, void* d_ws, size_t ws_size,
                              hipStream_t stream)
{
    const float* x   = (const float*)d_in[0];
    const int*   ei  = (const int*)d_in[1];
    const float* W1  = (const float*)d_in[2];
    const float* as1 = (const float*)d_in[3];
    const float* ad1 = (const float*)d_in[4];
    const float* b1  = (const float*)d_in[5];
    const float* W2  = (const float*)d_in[6];
    const float* as2 = (const float*)d_in[7];
    const float* ad2 = (const float*)d_in[8];
    const float* b2  = (const float*)d_in[9];
    const float* dW1 = (const float*)d_in[10];
    const float* db1 = (const float*)d_in[11];
    const float* dW2 = (const float*)d_in[12];
    const float* db2 = (const float*)d_in[13];

    const int N    = in_sizes[0] / IN_DIM;
    const int E    = in_sizes[1] / 2;
    const int Etot = E + N;

    // fixed-size region first (keeps every u16 array 16B-aligned for any N)
    unsigned short* W1f = (unsigned short*)d_ws;           // 32768 u16
    unsigned short* W2f = W1f + 32768;                     // 16384 u16
    float* u_s = (float*)(W2f + 16384);                    // 512 f32
    float* u_d = u_s + 512;                                // 512 f32
    unsigned short* xagg = (unsigned short*)(u_d + 512);   // N*512 u16
    unsigned short* xb   = xagg + (size_t)N * 512;         // N*128 u16
    unsigned short* h2b  = xb   + (size_t)N * IN_DIM;      // N*64  u16
    float* a_s1 = (float*)(h2b + (size_t)N * OUT_DIM);     // N*4
    float* a_d1 = a_s1 + (size_t)N * HEADS;                // N*4
    float* a_s2 = a_d1 + (size_t)N * HEADS;                // N
    float* a_d2 = a_s2 + (size_t)N;                        // N
    int* rowptr = (int*)(a_d2 + (size_t)N);                // N+1
    int* cursor = rowptr + (N + 1);                        // N
    int* col    = cursor + N;                              // Etot
    int* psum   = col + Etot;                              // 256

    const size_t needed = (size_t)N * 1456 + (size_t)Etot * 4 + 103432;
    if (ws_size < needed) return;  // loud failure signature

    hipMemsetAsync(rowptr, 0, (size_t)(N + 1) * sizeof(int), stream);

    const int SC    = (N + 255) / 256;           // <=256 chunks (N=50k -> 196)
    const int mblk  = (N + 63) / 64;
    const int nblk4 = (N + 3) / 4;
    const int nchunk = (Etot + 2047) / 2048;     // ~2k edges per chunk
    const int bgrid  = nchunk * 8;               // 8 bins x chunks
    w1f_k     <<<25, 256, 0, stream>>>(W1, W2, as1, ad1, W1f, W2f, u_s, u_d);
    xprep_deg_k<<<bgrid + nblk4, 256, 0, stream>>>(x, u_s, u_d, xb, a_s1, a_d1,
                                                   N, ei, E, Etot, rowptr,
                                                   bgrid, nchunk);
    scanA_k   <<<SC, 256, 0, stream>>>(rowptr, psum, N);
    scanC_k   <<<SC, 256, 0, stream>>>(rowptr, cursor, psum, N, SC);
    fill_k    <<<bgrid, 256, 0, stream>>>(ei, E, Etot, cursor, col, N);
    agg1x_k   <<<nblk4, 256, 0, stream>>>(rowptr, col, a_s1, a_d1, xb, xagg, N);
    gemm12_k  <<<mblk, 256, 0, stream>>>(xagg, W1f, b1, W2f, as2, ad2, h2b,
                                         a_s2, a_d2, N);
    agg2_k    <<<nblk4, 256, 0, stream>>>(rowptr, col, a_s2, a_d2, h2b, b2,
                                          (float*)d_out, N);
    dec_k     <<<(N + 31) / 32, 256, 0, stream>>>((const float*)d_out, dW1, db1,
                                                  dW2, db2,
                                                  (float*)d_out + (size_t)N * OUT_DIM, N);
}

// Round 11
// 336.908 us; speedup vs baseline: 1.0285x; 1.0285x over previous
//
#include <hip/hip_runtime.h>
#include <hip/hip_bf16.h>

// GAT-GAE forward: 2x GATConv + normalize + MLP decoder. fp32 I/O, int32 edges.
// Round 20: deg DE-BINNED (single pass). R19's null result (reordering deg
// blocks changed WRITE_SIZE by 0 bytes) shows device-scope atomics execute at
// the memory-side coherence point -- XCD binning buys nothing for atomics
// (R12's binning win was fill_k's plain STORES write-combining in L2, which
// stays). Binned deg was pure waste: 8x redundant dst scans, 8x blocks.
// Now deg = one thread per edge, one atomic, nchunk blocks at grid front.
//
// Workspace (bytes): W1f 64K | W2f 32K | u_s 2K | u_d 2K |
//   xagg u16[N*512] | xb u16[N*128] | h2b u16[N*64] |
//   a_s1 f32[4N] | a_d1 f32[4N] | a_s2 f32[N] | a_d2 f32[N] |
//   rowptr int[N+1] | cursor int[N] | col int[Etot] | psum int[256]

#define IN_DIM   128
#define C1       256   // HEADS*HID
#define HEADS    4
#define HID      64
#define OUT_DIM  64

typedef __attribute__((ext_vector_type(8))) short short8;
typedef __attribute__((ext_vector_type(4))) float f32x4;
typedef __attribute__((ext_vector_type(2))) float f32x2;

__device__ __forceinline__ float lrelu(float x) { return x > 0.f ? x : 0.2f * x; }
__device__ __forceinline__ float elu1(float x)  { return x > 0.f ? x : (__expf(x) - 1.f); }
__device__ __forceinline__ float expc(float x)  { return __expf(fminf(x, 60.f)); }
__device__ __forceinline__ float bfu(unsigned int u) {
    union { unsigned int i; float f; } c; c.i = u << 16; return c.f;
}
__device__ __forceinline__ unsigned short pk(float f) {
    union { float f; unsigned int i; } c; c.f = f;
    return (unsigned short)((c.i + 0x7fffu + ((c.i >> 16) & 1u)) >> 16);
}
// acc.{lo,hi} += x.{lo,hi} * wpair.lo   (both result halves read src1 LO)
__device__ __forceinline__ void pkfma_lo(f32x2& acc, const f32x2 x, const f32x2 wp) {
    asm("v_pk_fma_f32 %0, %1, %2, %0 op_sel_hi:[1,0,1]"
        : "+v"(acc) : "v"(x), "v"(wp));
}
// acc.{lo,hi} += x.{lo,hi} * wpair.hi   (both result halves read src1 HI)
__device__ __forceinline__ void pkfma_hi(f32x2& acc, const f32x2 x, const f32x2 wp) {
    asm("v_pk_fma_f32 %0, %1, %2, %0 op_sel:[0,1,0] op_sel_hi:[1,1,1]"
        : "+v"(acc) : "v"(x), "v"(wp));
}
// unpack bf16 pair (lo,hi of u32) into packed f32x2
__device__ __forceinline__ f32x2 bf2up(unsigned int u) {
    union { unsigned int i[2]; f32x2 f; } c;
    c.i[0] = u << 16;
    c.i[1] = u & 0xffff0000u;
    return c.f;
}

// ======== weight prepack (merged): B-fragment order for 16x16x32 bf16 =======
// Blocks 0..15: W1 [128][256] fp32 -> W1f[((nt*4+kc)*64 + lane)*8 + j] =
//   bf16(W1[(kc*32 + (lane>>4)*8 + j)*256 + nt*16 + (lane&15)])
// Block 16: u_s[h*128+k] = sum_c W1[k][h*64+c]*att_src1[h][c]; u_d likewise.
// Blocks 17..24: W2 [256][64] fp32 -> W2f[((nt*8+kc)*64 + lane)*8 + j]
__global__ __launch_bounds__(256) void w1f_k(const float* __restrict__ W1,
                                             const float* __restrict__ W2,
                                             const float* __restrict__ as1,
                                             const float* __restrict__ ad1,
                                             unsigned short* __restrict__ W1f,
                                             unsigned short* __restrict__ W2f,
                                             float* __restrict__ u_s,
                                             float* __restrict__ u_d)
{
    const int b = blockIdx.x;
    if (b == 16) {
        for (int idx = threadIdx.x; idx < 512; idx += 256) {
            const int h = idx >> 7, k = idx & 127;
            float ss = 0.f, dd = 0.f;
            #pragma unroll 4
            for (int c = 0; c < 64; ++c) {
                const float wv = W1[k * 256 + h * 64 + c];
                ss += wv * as1[h * 64 + c];
                dd += wv * ad1[h * 64 + c];
            }
            u_s[idx] = ss;
            u_d[idx] = dd;
        }
        return;
    }
    if (b >= 17) {   // W2f pack
        const int idx = (b - 17) * 256 + threadIdx.x;   // 2048 lane-entries
        if (idx >= 32 * 64) return;
        const int lane = idx & 63, e = idx >> 6;
        const int nt = e >> 3, kc = e & 7, q = lane >> 4, c = lane & 15;
        unsigned short tmp[8];
        #pragma unroll
        for (int j = 0; j < 8; ++j)
            tmp[j] = pk(W2[(kc * 32 + q * 8 + j) * 64 + nt * 16 + c]);
        ushort4* dst = (ushort4*)(W2f + (size_t)idx * 8);
        dst[0] = make_ushort4(tmp[0], tmp[1], tmp[2], tmp[3]);
        dst[1] = make_ushort4(tmp[4], tmp[5], tmp[6], tmp[7]);
        return;
    }
    const int idx = b * 256 + threadIdx.x;   // 4096 lane-entries
    if (idx >= 64 * 64) return;
    const int lane = idx & 63, e = idx >> 6;
    const int nt = e >> 2, kc = e & 3, q = lane >> 4, c = lane & 15;
    unsigned short tmp[8];
    #pragma unroll
    for (int j = 0; j < 8; ++j)
        tmp[j] = pk(W1[(kc * 32 + q * 8 + j) * 256 + nt * 16 + c]);
    ushort4* dst = (ushort4*)(W1f + (size_t)idx * 8);
    dst[0] = make_ushort4(tmp[0], tmp[1], tmp[2], tmp[3]);
    dst[1] = make_ushort4(tmp[4], tmp[5], tmp[6], tmp[7]);
}

// ==== deg (blocks < dgrid, single-pass, un-binned) + xprep (rest) ==========
// deg: 1 thread/edge, 1 device-scope atomic (atomics execute at the fabric
// coherence point -- binning/placement has no effect, R19 null result).
// xprep: 1 wave/node, lane l owns ch 2l,2l+1; a_s1[n,h] = x[n]·u_s[h].
__global__ __launch_bounds__(256) void xprep_deg_k(
    const float* __restrict__ x, const float* __restrict__ u_s,
    const float* __restrict__ u_d, unsigned short* __restrict__ xb,
    float* __restrict__ a_s1, float* __restrict__ a_d1, int N,
    const int* __restrict__ ei, int E, int Etot, int* __restrict__ rowptr,
    int dgrid)
{
    if (blockIdx.x < dgrid) {            // ---- deg part (single pass) ----
        const int per = (Etot + dgrid - 1) / dgrid;
        const int e0 = blockIdx.x * per, e1 = min(e0 + per, Etot);
        for (int e = e0 + threadIdx.x; e < e1; e += 256) {
            const int d = (e < E) ? ei[E + e] : e - E;
            atomicAdd(&rowptr[1 + d], 1);
        }
        return;
    }
    // ---- xprep part ----
    __shared__ float us[512], ud[512];
    const int t = threadIdx.x;
    for (int i = t; i < 512; i += 256) { us[i] = u_s[i]; ud[i] = u_d[i]; }
    __syncthreads();
    const int w = t >> 6, l = t & 63;
    const int n = (blockIdx.x - dgrid) * 4 + w;
    if (n >= N) return;
    const float2 xv = *(const float2*)&x[(size_t)n * IN_DIM + 2 * l];
    const unsigned int p2 =
        (unsigned int)pk(xv.x) | ((unsigned int)pk(xv.y) << 16);
    *(unsigned int*)&xb[(size_t)n * IN_DIM + 2 * l] = p2;
    #pragma unroll
    for (int h = 0; h < 4; ++h) {
        float ps = xv.x * us[h * 128 + 2 * l] + xv.y * us[h * 128 + 2 * l + 1];
        float pd = xv.x * ud[h * 128 + 2 * l] + xv.y * ud[h * 128 + 2 * l + 1];
        #pragma unroll
        for (int off = 1; off < 64; off <<= 1) {
            ps += __shfl_xor(ps, off, 64);
            pd += __shfl_xor(pd, off, 64);
        }
        if (l == 0) {
            a_s1[n * 4 + h] = ps;
            a_d1[n * 4 + h] = pd;
        }
    }
}

__device__ __forceinline__ int blk_incl_scan(int v, int t) {
    __shared__ int wsum[4];
    const int lane = t & 63, wid = t >> 6;
    int s = v;
    #pragma unroll
    for (int off = 1; off < 64; off <<= 1) {
        const int u = __shfl_up(s, off, 64);
        if (lane >= off) s += u;
    }
    if (lane == 63) wsum[wid] = s;
    __syncthreads();
    int add = 0;
    #pragma unroll
    for (int k = 0; k < 4; ++k) if (k < wid) add += wsum[k];
    __syncthreads();
    return s + add;
}

__global__ __launch_bounds__(256) void scanA_k(const int* __restrict__ rowptr,
                                               int* __restrict__ psum, int N)
{
    const int t = threadIdx.x;
    const int i = blockIdx.x * 256 + t;
    int v = (i < N) ? rowptr[1 + i] : 0;
    #pragma unroll
    for (int off = 1; off < 64; off <<= 1) v += __shfl_xor(v, off, 64);
    __shared__ int ws[4];
    if ((t & 63) == 0) ws[t >> 6] = v;
    __syncthreads();
    if (t == 0) psum[blockIdx.x] = ws[0] + ws[1] + ws[2] + ws[3];
}

// scanC with inline base computation: base = sum(psum[0..blockIdx.x)).
// psum holds UNSCANNED per-chunk totals from scanA; SC <= 256.
__global__ __launch_bounds__(256) void scanC_k(int* __restrict__ rowptr,
                                               int* __restrict__ cursor,
                                               const int* __restrict__ psum,
                                               int N, int SC)
{
    const int t = threadIdx.x;
    int s = (t < SC && t < (int)blockIdx.x) ? psum[t] : 0;
    #pragma unroll
    for (int off = 1; off < 64; off <<= 1) s += __shfl_xor(s, off, 64);
    __shared__ int bsum[4];
    if ((t & 63) == 0) bsum[t >> 6] = s;
    __syncthreads();
    const int base = bsum[0] + bsum[1] + bsum[2] + bsum[3];
    __syncthreads();                      // bsum reuse safety vs blk_incl_scan
    const int i = blockIdx.x * 256 + t;
    const int v = (i < N) ? rowptr[1 + i] : 0;
    const int inc = blk_incl_scan(v, t);
    if (i < N) {
        rowptr[1 + i] = base + inc;
        cursor[i]     = base + inc - v;
    }
}

// Binned fill: bin's col region stays in the local XCD L2 and accumulates
// FULL dirty lines before writeback (R12: 55MB -> ~3.4MB HBM writes).
// (Binning DOES matter here: col[pos] is a plain store, write-combined in L2.)
__global__ __launch_bounds__(256) void fill_k(const int* __restrict__ ei, int E,
                                              int Etot, int* __restrict__ cursor,
                                              int* __restrict__ col, int N)
{
    const int bin = blockIdx.x & 7;
    const int chunk = blockIdx.x >> 3, nchunk = gridDim.x >> 3;
    const int per = (Etot + nchunk - 1) / nchunk;
    const int e0 = chunk * per, e1 = min(e0 + per, Etot);
    const int lo = (int)(((long long)N * bin) >> 3);
    const int hi = (int)(((long long)N * (bin + 1)) >> 3);
    for (int e = e0 + threadIdx.x; e < e1; e += 256) {
        const int d = (e < E) ? ei[E + e] : e - E;
        if (d >= lo && d < hi) {
            const int s = (e < E) ? ei[e] : d;
            const int pos = atomicAdd(&cursor[d], 1);
            col[pos] = s;
        }
    }
}

// ====== Layer-1 aggregate over x: xagg[n,h,:] = (sum_e w_e^h x[src]) / sum w ==
// 1 wave/node; lane l owns channels (2l,2l+1) for all 4 heads (packed f32x2
// per head, v_pk_fma_f32 with op_sel half-select). Per 64-edge chunk: lane l
// stages edge (t0+l)'s {scol, float4 weights} into per-wave LDS; consume loop
// reads them via uniform ds_read (broadcast). 8 gathers in flight (verified
// optimum: 16-deep raised VGPR to 64 and cost 22% -- R16).
__global__ __launch_bounds__(256) void agg1x_k(
    const int* __restrict__ rowptr, const int* __restrict__ col,
    const float* __restrict__ a_s1, const float* __restrict__ a_d1,
    const unsigned short* __restrict__ xb, unsigned short* __restrict__ xagg,
    int N)
{
    __shared__ int    scolS[4][64];
    __shared__ float4 w4S[4][64];
    const int t = threadIdx.x, w = t >> 6, l = t & 63;
    const int n = blockIdx.x * 4 + w;
    if (n >= N) return;
    const int beg = rowptr[n], end = rowptr[n + 1];
    const float4 dv = *(const float4*)&a_d1[n * 4];
    float4 ws = {0.f, 0.f, 0.f, 0.f};
    f32x2 acc[4] = {{0.f,0.f},{0.f,0.f},{0.f,0.f},{0.f,0.f}};
    const unsigned short* xbl = xb + 2 * l;
    for (int t0 = beg; t0 < end; t0 += 64) {
        const int m = min(64, end - t0);
        const int p = t0 + l;
        int sc = 0;
        float4 wv = {0.f, 0.f, 0.f, 0.f};
        if (p < end) {
            sc = col[p];
            const float4 av = *(const float4*)&a_s1[sc * 4];
            wv.x = expc(lrelu(av.x + dv.x));
            wv.y = expc(lrelu(av.y + dv.y));
            wv.z = expc(lrelu(av.z + dv.z));
            wv.w = expc(lrelu(av.w + dv.w));
            ws.x += wv.x; ws.y += wv.y; ws.z += wv.z; ws.w += wv.w;
        }
        scolS[w][l] = sc;
        w4S[w][l]   = wv;
        __threadfence_block();           // within-wave LDS write->read order
        for (int j0 = 0; j0 < m; j0 += 8) {
            const int4 s0 = *(const int4*)&scolS[w][j0];
            const int4 s1 = *(const int4*)&scolS[w][j0 + 4];
            const int su[8] = {s0.x, s0.y, s0.z, s0.w, s1.x, s1.y, s1.z, s1.w};
            unsigned int hv[8];
            #pragma unroll
            for (int u = 0; u < 8; ++u)   // 8 gathers in flight
                hv[u] = *(const unsigned int*)(xbl + (size_t)su[u] * IN_DIM);
            #pragma unroll
            for (int u = 0; u < 8; ++u) {
                const float* wb = (const float*)&w4S[w][j0 + u];
                const f32x2 wp01 = *(const f32x2*)(wb);      // {w0,w1}
                const f32x2 wp23 = *(const f32x2*)(wb + 2);  // {w2,w3}
                const f32x2 xv = bf2up(hv[u]);
                pkfma_lo(acc[0], xv, wp01);
                pkfma_hi(acc[1], xv, wp01);
                pkfma_lo(acc[2], xv, wp23);
                pkfma_hi(acc[3], xv, wp23);
            }
        }
    }
    #pragma unroll
    for (int off = 1; off < 64; off <<= 1) {
        ws.x += __shfl_xor(ws.x, off, 64);
        ws.y += __shfl_xor(ws.y, off, 64);
        ws.z += __shfl_xor(ws.z, off, 64);
        ws.w += __shfl_xor(ws.w, off, 64);
    }
    const float i0 = 1.f / (ws.x + 1e-16f), i1 = 1.f / (ws.y + 1e-16f);
    const float i2 = 1.f / (ws.z + 1e-16f), i3 = 1.f / (ws.w + 1e-16f);
    unsigned short* out = xagg + (size_t)n * 512 + 2 * l;
    *(unsigned int*)(out)       = (unsigned int)pk(acc[0][0] * i0) |
                                  ((unsigned int)pk(acc[0][1] * i0) << 16);
    *(unsigned int*)(out + 128) = (unsigned int)pk(acc[1][0] * i1) |
                                  ((unsigned int)pk(acc[1][1] * i1) << 16);
    *(unsigned int*)(out + 256) = (unsigned int)pk(acc[2][0] * i2) |
                                  ((unsigned int)pk(acc[2][1] * i2) << 16);
    *(unsigned int*)(out + 384) = (unsigned int)pk(acc[3][0] * i3) |
                                  ((unsigned int)pk(acc[3][1] * i3) << 16);
}

// ====== Fused layer-1 + layer-2 GEMM (MFMA), LDS handoff (no hxb) ==========
// Phase 1 (old gemm1b): hx = elu(xagg @ W1 + b1) block-diagonal; epilogue
// lands in lds stride 264 -- the exact layout old gemm2 staged from global.
// Phase 2 (old gemm2): h2 = hx @ W2 + logits, reading lds directly. Each
// wave's phase-2 A-rows (16w+c) are the rows the same wave wrote in phase 1.
__global__ __launch_bounds__(256) void gemm12_k(
    const unsigned short* __restrict__ xagg, const unsigned short* __restrict__ W1f,
    const float* __restrict__ b1, const unsigned short* __restrict__ W2f,
    const float* __restrict__ as2, const float* __restrict__ ad2,
    unsigned short* __restrict__ h2b, float* __restrict__ a_s2,
    float* __restrict__ a_d2, int N)
{
    __shared__ short lds[64 * 264];
    const int t = threadIdx.x, w = t >> 6, l = t & 63;
    const int q = l >> 4, c = l & 15;
    const int n0 = blockIdx.x * 64;
    const int arow = 16 * w + c;
    // ---------------- phase 1: block-diag W1 ----------------
    f32x4 acc[16];
    #pragma unroll
    for (int nt = 0; nt < 16; ++nt) acc[nt] = (f32x4){0.f, 0.f, 0.f, 0.f};
    #pragma unroll
    for (int half = 0; half < 2; ++half) {
        if (half) __syncthreads();           // protect LDS reuse
        for (int i = t; i < 64 * 32; i += 256) {
            const int r = i >> 5, ch = (i & 31) * 8;
            const int rn = min(n0 + r, N - 1);
            *(short8*)&lds[r * 264 + ch] =
                *(const short8*)&xagg[(size_t)rn * 512 + half * 256 + ch];
        }
        __syncthreads();
        #pragma unroll
        for (int hh = 0; hh < 2; ++hh) {
            const int h = half * 2 + hh;
            short8 afr[4];
            #pragma unroll
            for (int kc = 0; kc < 4; ++kc)
                afr[kc] = *(const short8*)&lds[arow * 264 + hh * 128 + kc * 32 + q * 8];
            #pragma unroll
            for (int nt = 0; nt < 4; ++nt) {
                #pragma unroll
                for (int kc = 0; kc < 4; ++kc) {
                    const short8 bfr = *(const short8*)(W1f +
                        ((size_t)((h * 4 + nt) * 4 + kc) * 64 + l) * 8);
                    acc[h * 4 + nt] = __builtin_amdgcn_mfma_f32_16x16x32_bf16(
                        afr[kc], bfr, acc[h * 4 + nt], 0, 0, 0);
                }
            }
        }
    }
    __syncthreads();
    #pragma unroll
    for (int nt = 0; nt < 16; ++nt)
        #pragma unroll
        for (int r = 0; r < 4; ++r) {
            const float v = elu1(acc[nt][r] + b1[nt * 16 + c]);
            lds[(16 * w + q * 4 + r) * 264 + nt * 16 + c] = (short)pk(v);
        }
    __syncthreads();
    // ---------------- phase 2: W2 + logits ----------------
    short8 afr2[8];
    #pragma unroll
    for (int kc = 0; kc < 8; ++kc)
        afr2[kc] = *(const short8*)&lds[arow * 264 + kc * 32 + q * 8];
    f32x4 acc2[4];
    #pragma unroll
    for (int nt = 0; nt < 4; ++nt) acc2[nt] = (f32x4){0.f, 0.f, 0.f, 0.f};
    #pragma unroll
    for (int nt = 0; nt < 4; ++nt) {
        #pragma unroll
        for (int kc = 0; kc < 8; ++kc) {
            const short8 bfr =
                *(const short8*)(W2f + ((size_t)(nt * 8 + kc) * 64 + l) * 8);
            acc2[nt] = __builtin_amdgcn_mfma_f32_16x16x32_bf16(afr2[kc], bfr,
                                                               acc2[nt], 0, 0, 0);
        }
    }
    {
        float vsr[4] = {0.f, 0.f, 0.f, 0.f}, vdr[4] = {0.f, 0.f, 0.f, 0.f};
        #pragma unroll
        for (int nt = 0; nt < 4; ++nt) {
            const float sa = as2[nt * 16 + c], da = ad2[nt * 16 + c];
            #pragma unroll
            for (int r = 0; r < 4; ++r) {
                vsr[r] += acc2[nt][r] * sa;
                vdr[r] += acc2[nt][r] * da;
            }
        }
        #pragma unroll
        for (int r = 0; r < 4; ++r) {
            #pragma unroll
            for (int off = 1; off < 16; off <<= 1) {
                vsr[r] += __shfl_xor(vsr[r], off, 64);
                vdr[r] += __shfl_xor(vdr[r], off, 64);
            }
            const int node = n0 + 16 * w + q * 4 + r;
            if (c == 0 && node < N) {
                a_s2[node] = vsr[r];
                a_d2[node] = vdr[r];
            }
        }
    }
    __syncthreads();
    #pragma unroll
    for (int nt = 0; nt < 4; ++nt)
        #pragma unroll
        for (int r = 0; r < 4; ++r)
            lds[(16 * w + q * 4 + r) * 72 + nt * 16 + c] = (short)pk(acc2[nt][r]);
    __syncthreads();
    for (int i = t; i < 64 * 8; i += 256) {
        const int r = i >> 3, ch = (i & 7) * 8;
        const int node = n0 + r;
        if (node < N)
            *(short8*)&h2b[(size_t)node * OUT_DIM + ch] =
                *(const short8*)&lds[r * 72 + ch];
    }
}

// ====== Layer-2 aggregate: 1 wave/node, lane = 2 ch; LDS-staged weights =====
// Staged int2{scol,w} IS the 64-bit pair for pk_fma (w in hi half).
__global__ __launch_bounds__(256) void agg2_k(
    const int* __restrict__ rowptr, const int* __restrict__ col,
    const float* __restrict__ a_s2, const float* __restrict__ a_d2,
    const unsigned short* __restrict__ h2b, const float* __restrict__ b2,
    float* __restrict__ zout, int N)
{
    __shared__ int2 swS[4][64];
    const int t = threadIdx.x, w = t >> 6, l = t & 63;
    const int n = blockIdx.x * 4 + w;
    if (n >= N) return;
    const int beg = rowptr[n], end = rowptr[n + 1];
    const float dn = a_d2[n];
    const int half = l >> 5, c2 = l & 31;     // lane owns ch 2*c2, 2*c2+1
    f32x2 acc = {0.f, 0.f};
    float wsum = 0.f;
    const unsigned short* h2l = h2b + 2 * c2;
    for (int t0 = beg; t0 < end; t0 += 64) {
        const int m = min(64, end - t0);
        const int p = t0 + l;
        int sc = 0; float wv = 0.f;
        if (p < end) {
            sc = col[p];
            wv = expc(lrelu(a_s2[sc] + dn));
            wsum += wv;
        }
        swS[w][l] = make_int2(sc, __float_as_int(wv));
        __threadfence_block();           // within-wave LDS write->read order
        const int pairs = (m + 1) >> 1;
        for (int j0 = 0; j0 < pairs; j0 += 8) {
            int2 sv[8];
            #pragma unroll
            for (int u = 0; u < 8; ++u)
                sv[u] = swS[w][2 * (j0 + u) + half];
            unsigned int hv[8];
            #pragma unroll
            for (int u = 0; u < 8; ++u)
                hv[u] = *(const unsigned int*)(h2l + (size_t)sv[u].x * OUT_DIM);
            #pragma unroll
            for (int u = 0; u < 8; ++u) {
                union { int2 i; f32x2 f; } cv; cv.i = sv[u];
                pkfma_hi(acc, bf2up(hv[u]), cv.f);
            }
        }
    }
    float a0 = acc[0], a1 = acc[1];
    a0 += __shfl_xor(a0, 32, 64);
    a1 += __shfl_xor(a1, 32, 64);
    #pragma unroll
    for (int off = 1; off < 64; off <<= 1) wsum += __shfl_xor(wsum, off, 64);
    const float inv = 1.f / (wsum + 1e-16f);
    float z0 = a0 * inv + b2[2 * c2];
    float z1 = a1 * inv + b2[2 * c2 + 1];
    float sq = z0 * z0 + z1 * z1;
    #pragma unroll
    for (int off = 1; off < 32; off <<= 1) sq += __shfl_xor(sq, off, 64);
    const float rn = 1.f / fmaxf(sqrtf(sq), 1e-12f);
    if (l < 32) {
        float2 o; o.x = z0 * rn; o.y = z1 * rn;
        *(float2*)&zout[(size_t)n * OUT_DIM + 2 * c2] = o;
    }
}

// ================= Decoder: x_hat = elu(z@dW1+db1)@dW2+db2 =================
__global__ __launch_bounds__(256) void dec_k(
    const float* __restrict__ z,
    const float* __restrict__ dW1, const float* __restrict__ db1,
    const float* __restrict__ dW2, const float* __restrict__ db2,
    float* __restrict__ xhat, int N)
{
    __shared__ float zs[32 * 64];
    __shared__ float ts[32 * 64];
    const int t = threadIdx.x;
    const int n0 = blockIdx.x * 32;
    for (int i = t; i < 32 * 64; i += 256) {
        const int nb_l = i >> 6, k = i & 63;
        const int n = min(n0 + nb_l, N - 1);
        zs[(nb_l >> 3) * 512 + k * 8 + (nb_l & 7)] = z[(size_t)n * OUT_DIM + k];
    }
    __syncthreads();
    const int w = t >> 6, l = t & 63;
    const float* zw = zs + w * 512;
    float* tw = ts + w * 512;
    float acc[8] = {0.f, 0.f, 0.f, 0.f, 0.f, 0.f, 0.f, 0.f};
    #pragma unroll 4
    for (int k = 0; k < 64; ++k) {
        const float wv = dW1[k * HID + l];
        const float4 xa = *(const float4*)&zw[k * 8];
        const float4 xb = *(const float4*)&zw[k * 8 + 4];
        acc[0] += xa.x * wv; acc[1] += xa.y * wv;
        acc[2] += xa.z * wv; acc[3] += xa.w * wv;
        acc[4] += xb.x * wv; acc[5] += xb.y * wv;
        acc[6] += xb.z * wv; acc[7] += xb.w * wv;
    }
    const float bb = db1[l];
    #pragma unroll
    for (int nb = 0; nb < 8; ++nb) tw[l * 8 + nb] = elu1(acc[nb] + bb);
    __syncthreads();
    float a0[8] = {0.f, 0.f, 0.f, 0.f, 0.f, 0.f, 0.f, 0.f};
    float a1[8] = {0.f, 0.f, 0.f, 0.f, 0.f, 0.f, 0.f, 0.f};
    #pragma unroll 2
    for (int k = 0; k < 64; ++k) {
        const float w0 = dW2[k * IN_DIM + l];
        const float w1 = dW2[k * IN_DIM + 64 + l];
        const float4 xa = *(const float4*)&tw[k * 8];
        const float4 xb = *(const float4*)&tw[k * 8 + 4];
        const float xv[8] = {xa.x, xa.y, xa.z, xa.w, xb.x, xb.y, xb.z, xb.w};
        #pragma unroll
        for (int nb = 0; nb < 8; ++nb) {
            a0[nb] += xv[nb] * w0;
            a1[nb] += xv[nb] * w1;
        }
    }
    const float bb0 = db2[l], bb1 = db2[64 + l];
    #pragma unroll
    for (int nb = 0; nb < 8; ++nb) {
        const int n = n0 + w * 8 + nb;
        if (n >= N) break;
        xhat[(size_t)n * IN_DIM + l]      = a0[nb] + bb0;
        xhat[(size_t)n * IN_DIM + 64 + l] = a1[nb] + bb1;
    }
}

extern "C" void kernel_launch(void* const* d_in, const int* in_sizes, int n_in,
                              void* d_out, int out_size, void* d_ws, size_t ws_size,
                              hipStream_t stream)
{
    const float* x   = (const float*)d_in[0];
    const int*   ei  = (const int*)d_in[1];
    const float* W1  = (const float*)d_in[2];
    const float* as1 = (const float*)d_in[3];
    const float* ad1 = (const float*)d_in[4];
    const float* b1  = (const float*)d_in[5];
    const float* W2  = (const float*)d_in[6];
    const float* as2 = (const float*)d_in[7];
    const float* ad2 = (const float*)d_in[8];
    const float* b2  = (const float*)d_in[9];
    const float* dW1 = (const float*)d_in[10];
    const float* db1 = (const float*)d_in[11];
    const float* dW2 = (const float*)d_in[12];
    const float* db2 = (const float*)d_in[13];

    const int N    = in_sizes[0] / IN_DIM;
    const int E    = in_sizes[1] / 2;
    const int Etot = E + N;

    // fixed-size region first (keeps every u16 array 16B-aligned for any N)
    unsigned short* W1f = (unsigned short*)d_ws;           // 32768 u16
    unsigned short* W2f = W1f + 32768;                     // 16384 u16
    float* u_s = (float*)(W2f + 16384);                    // 512 f32
    float* u_d = u_s + 512;                                // 512 f32
    unsigned short* xagg = (unsigned short*)(u_d + 512);   // N*512 u16
    unsigned short* xb   = xagg + (size_t)N * 512;         // N*128 u16
    unsigned short* h2b  = xb   + (size_t)N * IN_DIM;      // N*64  u16
    float* a_s1 = (float*)(h2b + (size_t)N * OUT_DIM);     // N*4
    float* a_d1 = a_s1 + (size_t)N * HEADS;                // N*4
    float* a_s2 = a_d1 + (size_t)N * HEADS;                // N
    float* a_d2 = a_s2 + (size_t)N;                        // N
    int* rowptr = (int*)(a_d2 + (size_t)N);                // N+1
    int* cursor = rowptr + (N + 1);                        // N
    int* col    = cursor + N;                              // Etot
    int* psum   = col + Etot;                              // 256

    const size_t needed = (size_t)N * 1456 + (size_t)Etot * 4 + 103432;
    if (ws_size < needed) return;  // loud failure signature

    hipMemsetAsync(rowptr, 0, (size_t)(N + 1) * sizeof(int), stream);

    const int SC    = (N + 255) / 256;           // <=256 chunks (N=50k -> 196)
    const int mblk  = (N + 63) / 64;
    const int nblk4 = (N + 3) / 4;
    const int nchunk = (Etot + 2047) / 2048;     // ~2k edges per chunk
    const int bgrid  = nchunk * 8;               // 8 bins x chunks (fill only)
    w1f_k     <<<25, 256, 0, stream>>>(W1, W2, as1, ad1, W1f, W2f, u_s, u_d);
    xprep_deg_k<<<nchunk + nblk4, 256, 0, stream>>>(x, u_s, u_d, xb, a_s1,
                                                    a_d1, N, ei, E, Etot,
                                                    rowptr, nchunk);
    scanA_k   <<<SC, 256, 0, stream>>>(rowptr, psum, N);
    scanC_k   <<<SC, 256, 0, stream>>>(rowptr, cursor, psum, N, SC);
    fill_k    <<<bgrid, 256, 0, stream>>>(ei, E, Etot, cursor, col, N);
    agg1x_k   <<<nblk4, 256, 0, stream>>>(rowptr, col, a_s1, a_d1, xb, xagg, N);
    gemm12_k  <<<mblk, 256, 0, stream>>>(xagg, W1f, b1, W2f, as2, ad2, h2b,
                                         a_s2, a_d2, N);
    agg2_k    <<<nblk4, 256, 0, stream>>>(rowptr, col, a_s2, a_d2, h2b, b2,
                                          (float*)d_out, N);
    dec_k     <<<(N + 31) / 32, 256, 0, stream>>>((const float*)d_out, dW1, db1,
                                                  dW2, db2,
                                                  (float*)d_out + (size_t)N * OUT_DIM, N);
}

// Round 12
// 310.885 us; speedup vs baseline: 1.1146x; 1.0837x over previous
//
#include <hip/hip_runtime.h>
#include <hip/hip_bf16.h>

// GAT-GAE forward: 2x GATConv + normalize + MLP decoder. fp32 I/O, int32 edges.
// Round 21: CSR build replaced by a 2-level counting sort. R19/R20 proved
// device-scope atomics execute memory-side (~32B RMW each, placement- and
// cache-insensitive, ~15G/s): deg+fill's 1.7M atomics ~= 100us wall. New path:
//   cA (merged w/ xprep): LDS range-histogram per edge chunk -> 81k atomics
//   scanR: exclusive scan of NR<=256 range totals (1 block)
//   scat:  LDS histogram + 1 ticket atomic per (block,range) (81k w/ return),
//          plain stores of packed (src | local_dst<<24) into range buckets
//   rsort: per-range counting sort in LDS -> rowptr + col, ZERO global atomics
// deg/scanA/scanC/fill and the rowptr memset all deleted. Edge order within a
// node changes (harmless: weighted sum). Requires N <= 2^24 and NR <= 256.
//
// Workspace: W1f 64K | W2f 32K | u_s 2K | u_d 2K | xagg u16[N*512] |
//   xb u16[N*128] | h2b u16[N*64] | a_s1 f32[4N] | a_d1 f32[4N] | a_s2 f32[N]
//   | a_d2 f32[N] | rowptr int[N+1] | col int[Etot] | eb u32[Etot] |
//   rtot int[256] | rbase int[256] | rcur int[256]

#define IN_DIM   128
#define C1       256   // HEADS*HID
#define HEADS    4
#define HID      64
#define OUT_DIM  64

typedef __attribute__((ext_vector_type(8))) short short8;
typedef __attribute__((ext_vector_type(4))) float f32x4;
typedef __attribute__((ext_vector_type(2))) float f32x2;

__device__ __forceinline__ float lrelu(float x) { return x > 0.f ? x : 0.2f * x; }
__device__ __forceinline__ float elu1(float x)  { return x > 0.f ? x : (__expf(x) - 1.f); }
__device__ __forceinline__ float expc(float x)  { return __expf(fminf(x, 60.f)); }
__device__ __forceinline__ float bfu(unsigned int u) {
    union { unsigned int i; float f; } c; c.i = u << 16; return c.f;
}
__device__ __forceinline__ unsigned short pk(float f) {
    union { float f; unsigned int i; } c; c.f = f;
    return (unsigned short)((c.i + 0x7fffu + ((c.i >> 16) & 1u)) >> 16);
}
// acc.{lo,hi} += x.{lo,hi} * wpair.lo   (both result halves read src1 LO)
__device__ __forceinline__ void pkfma_lo(f32x2& acc, const f32x2 x, const f32x2 wp) {
    asm("v_pk_fma_f32 %0, %1, %2, %0 op_sel_hi:[1,0,1]"
        : "+v"(acc) : "v"(x), "v"(wp));
}
// acc.{lo,hi} += x.{lo,hi} * wpair.hi   (both result halves read src1 HI)
__device__ __forceinline__ void pkfma_hi(f32x2& acc, const f32x2 x, const f32x2 wp) {
    asm("v_pk_fma_f32 %0, %1, %2, %0 op_sel:[0,1,0] op_sel_hi:[1,1,1]"
        : "+v"(acc) : "v"(x), "v"(wp));
}
// unpack bf16 pair (lo,hi of u32) into packed f32x2
__device__ __forceinline__ f32x2 bf2up(unsigned int u) {
    union { unsigned int i[2]; f32x2 f; } c;
    c.i[0] = u << 16;
    c.i[1] = u & 0xffff0000u;
    return c.f;
}

// ======== weight prepack (merged): B-fragment order for 16x16x32 bf16 =======
__global__ __launch_bounds__(256) void w1f_k(const float* __restrict__ W1,
                                             const float* __restrict__ W2,
                                             const float* __restrict__ as1,
                                             const float* __restrict__ ad1,
                                             unsigned short* __restrict__ W1f,
                                             unsigned short* __restrict__ W2f,
                                             float* __restrict__ u_s,
                                             float* __restrict__ u_d)
{
    const int b = blockIdx.x;
    if (b == 16) {
        for (int idx = threadIdx.x; idx < 512; idx += 256) {
            const int h = idx >> 7, k = idx & 127;
            float ss = 0.f, dd = 0.f;
            #pragma unroll 4
            for (int c = 0; c < 64; ++c) {
                const float wv = W1[k * 256 + h * 64 + c];
                ss += wv * as1[h * 64 + c];
                dd += wv * ad1[h * 64 + c];
            }
            u_s[idx] = ss;
            u_d[idx] = dd;
        }
        return;
    }
    if (b >= 17) {   // W2f pack
        const int idx = (b - 17) * 256 + threadIdx.x;   // 2048 lane-entries
        if (idx >= 32 * 64) return;
        const int lane = idx & 63, e = idx >> 6;
        const int nt = e >> 3, kc = e & 7, q = lane >> 4, c = lane & 15;
        unsigned short tmp[8];
        #pragma unroll
        for (int j = 0; j < 8; ++j)
            tmp[j] = pk(W2[(kc * 32 + q * 8 + j) * 64 + nt * 16 + c]);
        ushort4* dst = (ushort4*)(W2f + (size_t)idx * 8);
        dst[0] = make_ushort4(tmp[0], tmp[1], tmp[2], tmp[3]);
        dst[1] = make_ushort4(tmp[4], tmp[5], tmp[6], tmp[7]);
        return;
    }
    const int idx = b * 256 + threadIdx.x;   // 4096 lane-entries
    if (idx >= 64 * 64) return;
    const int lane = idx & 63, e = idx >> 6;
    const int nt = e >> 2, kc = e & 3, q = lane >> 4, c = lane & 15;
    unsigned short tmp[8];
    #pragma unroll
    for (int j = 0; j < 8; ++j)
        tmp[j] = pk(W1[(kc * 32 + q * 8 + j) * 256 + nt * 16 + c]);
    ushort4* dst = (ushort4*)(W1f + (size_t)idx * 8);
    dst[0] = make_ushort4(tmp[0], tmp[1], tmp[2], tmp[3]);
    dst[1] = make_ushort4(tmp[4], tmp[5], tmp[6], tmp[7]);
}

// ==== cA range-count (blocks < CA) + xprep (rest) ===========================
// cA: per-chunk LDS histogram over NR<=256 node-ranges (range = dst>>8), then
// one global atomicAdd per nonzero (block,range) -- ~81k atomics vs 850k.
// xprep: 1 wave/node, lane l owns ch 2l,2l+1; a_s1[n,h] = x[n]·u_s[h].
__global__ __launch_bounds__(256) void xprep_cnt_k(
    const float* __restrict__ x, const float* __restrict__ u_s,
    const float* __restrict__ u_d, unsigned short* __restrict__ xb,
    float* __restrict__ a_s1, float* __restrict__ a_d1, int N,
    const int* __restrict__ ei, int E, int Etot, int* __restrict__ rtot,
    int CA, int NR)
{
    if (blockIdx.x < CA) {               // ---- cA: range counting ----
        __shared__ int hist[256];
        const int t = threadIdx.x;
        for (int i = t; i < NR; i += 256) hist[i] = 0;
        __syncthreads();
        const int per = (Etot + CA - 1) / CA;
        const int e0 = blockIdx.x * per, e1 = min(e0 + per, Etot);
        for (int e = e0 + t; e < e1; e += 256) {
            const int d = (e < E) ? ei[E + e] : e - E;
            atomicAdd(&hist[d >> 8], 1);
        }
        __syncthreads();
        for (int i = t; i < NR; i += 256)
            if (hist[i]) atomicAdd(&rtot[i], hist[i]);
        return;
    }
    // ---- xprep part ----
    __shared__ float us[512], ud[512];
    const int t = threadIdx.x;
    for (int i = t; i < 512; i += 256) { us[i] = u_s[i]; ud[i] = u_d[i]; }
    __syncthreads();
    const int w = t >> 6, l = t & 63;
    const int n = (blockIdx.x - CA) * 4 + w;
    if (n >= N) return;
    const float2 xv = *(const float2*)&x[(size_t)n * IN_DIM + 2 * l];
    const unsigned int p2 =
        (unsigned int)pk(xv.x) | ((unsigned int)pk(xv.y) << 16);
    *(unsigned int*)&xb[(size_t)n * IN_DIM + 2 * l] = p2;
    #pragma unroll
    for (int h = 0; h < 4; ++h) {
        float ps = xv.x * us[h * 128 + 2 * l] + xv.y * us[h * 128 + 2 * l + 1];
        float pd = xv.x * ud[h * 128 + 2 * l] + xv.y * ud[h * 128 + 2 * l + 1];
        #pragma unroll
        for (int off = 1; off < 64; off <<= 1) {
            ps += __shfl_xor(ps, off, 64);
            pd += __shfl_xor(pd, off, 64);
        }
        if (l == 0) {
            a_s1[n * 4 + h] = ps;
            a_d1[n * 4 + h] = pd;
        }
    }
}

__device__ __forceinline__ int blk_incl_scan(int v, int t) {
    __shared__ int wsum[4];
    const int lane = t & 63, wid = t >> 6;
    int s = v;
    #pragma unroll
    for (int off = 1; off < 64; off <<= 1) {
        const int u = __shfl_up(s, off, 64);
        if (lane >= off) s += u;
    }
    if (lane == 63) wsum[wid] = s;
    __syncthreads();
    int add = 0;
    #pragma unroll
    for (int k = 0; k < 4; ++k) if (k < wid) add += wsum[k];
    __syncthreads();
    return s + add;
}

// scanR: exclusive scan of NR range totals -> rbase (and rcur copy);
// also writes the rowptr[N] = Etot sentinel. Single block, NR <= 256.
__global__ __launch_bounds__(256) void scanR_k(const int* __restrict__ rtot,
                                               int* __restrict__ rbase,
                                               int* __restrict__ rcur,
                                               int* __restrict__ rowptr,
                                               int NR, int N, int Etot)
{
    const int t = threadIdx.x;
    const int v = (t < NR) ? rtot[t] : 0;
    const int inc = blk_incl_scan(v, t);
    if (t < NR) {
        rbase[t] = inc - v;
        rcur[t]  = inc - v;
    }
    if (t == 0) rowptr[N] = Etot;
}

// scat: re-histogram chunk ranges in LDS, grab ONE ticket per (block,range)
// via atomicAdd-with-return, then plain stores of packed edges into the
// range bucket: eb[pos] = src | (dst&255)<<24. (src < 2^24 required.)
__global__ __launch_bounds__(256) void scat_k(const int* __restrict__ ei,
                                              int E, int Etot,
                                              int* __restrict__ rcur,
                                              unsigned int* __restrict__ eb,
                                              int CA, int NR)
{
    __shared__ int hist[256], base[256];
    const int t = threadIdx.x;
    for (int i = t; i < NR; i += 256) hist[i] = 0;
    __syncthreads();
    const int per = (Etot + CA - 1) / CA;
    const int e0 = blockIdx.x * per, e1 = min(e0 + per, Etot);
    for (int e = e0 + t; e < e1; e += 256) {
        const int d = (e < E) ? ei[E + e] : e - E;
        atomicAdd(&hist[d >> 8], 1);
    }
    __syncthreads();
    for (int i = t; i < NR; i += 256) {
        base[i] = hist[i] ? atomicAdd(&rcur[i], hist[i]) : 0;
        hist[i] = 0;                       // reuse as local cursor
    }
    __syncthreads();
    for (int e = e0 + t; e < e1; e += 256) {
        int s, d;
        if (e < E) { s = ei[e]; d = ei[E + e]; } else { s = d = e - E; }
        const int r = d >> 8;
        const int local = atomicAdd(&hist[r], 1);
        eb[base[r] + local] = (unsigned int)s | ((unsigned int)(d & 255) << 24);
    }
}

// rsort: one block per range; counting-sort the range's bucket by local node
// id entirely in LDS; write rowptr (node starts) + col (grouped sources).
// Zero global atomics; col writes land in one contiguous ~17KB region.
__global__ __launch_bounds__(256) void rsort_k(const unsigned int* __restrict__ eb,
                                               const int* __restrict__ rtot,
                                               const int* __restrict__ rbase,
                                               int* __restrict__ rowptr,
                                               int* __restrict__ col, int N)
{
    __shared__ int hist[256], off[256];
    const int r = blockIdx.x;
    const int t = threadIdx.x;
    hist[t] = 0;
    __syncthreads();
    const int e0 = rbase[r], cnt = rtot[r];
    for (int i = t; i < cnt; i += 256)
        atomicAdd(&hist[eb[e0 + i] >> 24], 1);
    __syncthreads();
    const int v = hist[t];
    const int inc = blk_incl_scan(v, t);
    off[t] = inc - v;
    const int node = r * 256 + t;
    if (node < N) rowptr[node] = e0 + off[t];
    hist[t] = 0;                           // reuse as per-node cursor
    __syncthreads();
    for (int i = t; i < cnt; i += 256) {
        const unsigned int ev = eb[e0 + i];
        const int ld = ev >> 24;
        const int local = atomicAdd(&hist[ld], 1);
        col[e0 + off[ld] + local] = (int)(ev & 0xFFFFFFu);
    }
}

// ====== Layer-1 aggregate over x: xagg[n,h,:] = (sum_e w_e^h x[src]) / sum w ==
__global__ __launch_bounds__(256) void agg1x_k(
    const int* __restrict__ rowptr, const int* __restrict__ col,
    const float* __restrict__ a_s1, const float* __restrict__ a_d1,
    const unsigned short* __restrict__ xb, unsigned short* __restrict__ xagg,
    int N)
{
    __shared__ int    scolS[4][64];
    __shared__ float4 w4S[4][64];
    const int t = threadIdx.x, w = t >> 6, l = t & 63;
    const int n = blockIdx.x * 4 + w;
    if (n >= N) return;
    const int beg = rowptr[n], end = rowptr[n + 1];
    const float4 dv = *(const float4*)&a_d1[n * 4];
    float4 ws = {0.f, 0.f, 0.f, 0.f};
    f32x2 acc[4] = {{0.f,0.f},{0.f,0.f},{0.f,0.f},{0.f,0.f}};
    const unsigned short* xbl = xb + 2 * l;
    for (int t0 = beg; t0 < end; t0 += 64) {
        const int m = min(64, end - t0);
        const int p = t0 + l;
        int sc = 0;
        float4 wv = {0.f, 0.f, 0.f, 0.f};
        if (p < end) {
            sc = col[p];
            const float4 av = *(const float4*)&a_s1[sc * 4];
            wv.x = expc(lrelu(av.x + dv.x));
            wv.y = expc(lrelu(av.y + dv.y));
            wv.z = expc(lrelu(av.z + dv.z));
            wv.w = expc(lrelu(av.w + dv.w));
            ws.x += wv.x; ws.y += wv.y; ws.z += wv.z; ws.w += wv.w;
        }
        scolS[w][l] = sc;
        w4S[w][l]   = wv;
        __threadfence_block();           // within-wave LDS write->read order
        for (int j0 = 0; j0 < m; j0 += 8) {
            const int4 s0 = *(const int4*)&scolS[w][j0];
            const int4 s1 = *(const int4*)&scolS[w][j0 + 4];
            const int su[8] = {s0.x, s0.y, s0.z, s0.w, s1.x, s1.y, s1.z, s1.w};
            unsigned int hv[8];
            #pragma unroll
            for (int u = 0; u < 8; ++u)   // 8 gathers in flight
                hv[u] = *(const unsigned int*)(xbl + (size_t)su[u] * IN_DIM);
            #pragma unroll
            for (int u = 0; u < 8; ++u) {
                const float* wb = (const float*)&w4S[w][j0 + u];
                const f32x2 wp01 = *(const f32x2*)(wb);      // {w0,w1}
                const f32x2 wp23 = *(const f32x2*)(wb + 2);  // {w2,w3}
                const f32x2 xv = bf2up(hv[u]);
                pkfma_lo(acc[0], xv, wp01);
                pkfma_hi(acc[1], xv, wp01);
                pkfma_lo(acc[2], xv, wp23);
                pkfma_hi(acc[3], xv, wp23);
            }
        }
    }
    #pragma unroll
    for (int off = 1; off < 64; off <<= 1) {
        ws.x += __shfl_xor(ws.x, off, 64);
        ws.y += __shfl_xor(ws.y, off, 64);
        ws.z += __shfl_xor(ws.z, off, 64);
        ws.w += __shfl_xor(ws.w, off, 64);
    }
    const float i0 = 1.f / (ws.x + 1e-16f), i1 = 1.f / (ws.y + 1e-16f);
    const float i2 = 1.f / (ws.z + 1e-16f), i3 = 1.f / (ws.w + 1e-16f);
    unsigned short* out = xagg + (size_t)n * 512 + 2 * l;
    *(unsigned int*)(out)       = (unsigned int)pk(acc[0][0] * i0) |
                                  ((unsigned int)pk(acc[0][1] * i0) << 16);
    *(unsigned int*)(out + 128) = (unsigned int)pk(acc[1][0] * i1) |
                                  ((unsigned int)pk(acc[1][1] * i1) << 16);
    *(unsigned int*)(out + 256) = (unsigned int)pk(acc[2][0] * i2) |
                                  ((unsigned int)pk(acc[2][1] * i2) << 16);
    *(unsigned int*)(out + 384) = (unsigned int)pk(acc[3][0] * i3) |
                                  ((unsigned int)pk(acc[3][1] * i3) << 16);
}

// ====== Fused layer-1 + layer-2 GEMM (MFMA), LDS handoff (no hxb) ==========
__global__ __launch_bounds__(256) void gemm12_k(
    const unsigned short* __restrict__ xagg, const unsigned short* __restrict__ W1f,
    const float* __restrict__ b1, const unsigned short* __restrict__ W2f,
    const float* __restrict__ as2, const float* __restrict__ ad2,
    unsigned short* __restrict__ h2b, float* __restrict__ a_s2,
    float* __restrict__ a_d2, int N)
{
    __shared__ short lds[64 * 264];
    const int t = threadIdx.x, w = t >> 6, l = t & 63;
    const int q = l >> 4, c = l & 15;
    const int n0 = blockIdx.x * 64;
    const int arow = 16 * w + c;
    // ---------------- phase 1: block-diag W1 ----------------
    f32x4 acc[16];
    #pragma unroll
    for (int nt = 0; nt < 16; ++nt) acc[nt] = (f32x4){0.f, 0.f, 0.f, 0.f};
    #pragma unroll
    for (int half = 0; half < 2; ++half) {
        if (half) __syncthreads();           // protect LDS reuse
        for (int i = t; i < 64 * 32; i += 256) {
            const int r = i >> 5, ch = (i & 31) * 8;
            const int rn = min(n0 + r, N - 1);
            *(short8*)&lds[r * 264 + ch] =
                *(const short8*)&xagg[(size_t)rn * 512 + half * 256 + ch];
        }
        __syncthreads();
        #pragma unroll
        for (int hh = 0; hh < 2; ++hh) {
            const int h = half * 2 + hh;
            short8 afr[4];
            #pragma unroll
            for (int kc = 0; kc < 4; ++kc)
                afr[kc] = *(const short8*)&lds[arow * 264 + hh * 128 + kc * 32 + q * 8];
            #pragma unroll
            for (int nt = 0; nt < 4; ++nt) {
                #pragma unroll
                for (int kc = 0; kc < 4; ++kc) {
                    const short8 bfr = *(const short8*)(W1f +
                        ((size_t)((h * 4 + nt) * 4 + kc) * 64 + l) * 8);
                    acc[h * 4 + nt] = __builtin_amdgcn_mfma_f32_16x16x32_bf16(
                        afr[kc], bfr, acc[h * 4 + nt], 0, 0, 0);
                }
            }
        }
    }
    __syncthreads();
    #pragma unroll
    for (int nt = 0; nt < 16; ++nt)
        #pragma unroll
        for (int r = 0; r < 4; ++r) {
            const float v = elu1(acc[nt][r] + b1[nt * 16 + c]);
            lds[(16 * w + q * 4 + r) * 264 + nt * 16 + c] = (short)pk(v);
        }
    __syncthreads();
    // ---------------- phase 2: W2 + logits ----------------
    short8 afr2[8];
    #pragma unroll
    for (int kc = 0; kc < 8; ++kc)
        afr2[kc] = *(const short8*)&lds[arow * 264 + kc * 32 + q * 8];
    f32x4 acc2[4];
    #pragma unroll
    for (int nt = 0; nt < 4; ++nt) acc2[nt] = (f32x4){0.f, 0.f, 0.f, 0.f};
    #pragma unroll
    for (int nt = 0; nt < 4; ++nt) {
        #pragma unroll
        for (int kc = 0; kc < 8; ++kc) {
            const short8 bfr =
                *(const short8*)(W2f + ((size_t)(nt * 8 + kc) * 64 + l) * 8);
            acc2[nt] = __builtin_amdgcn_mfma_f32_16x16x32_bf16(afr2[kc], bfr,
                                                               acc2[nt], 0, 0, 0);
        }
    }
    {
        float vsr[4] = {0.f, 0.f, 0.f, 0.f}, vdr[4] = {0.f, 0.f, 0.f, 0.f};
        #pragma unroll
        for (int nt = 0; nt < 4; ++nt) {
            const float sa = as2[nt * 16 + c], da = ad2[nt * 16 + c];
            #pragma unroll
            for (int r = 0; r < 4; ++r) {
                vsr[r] += acc2[nt][r] * sa;
                vdr[r] += acc2[nt][r] * da;
            }
        }
        #pragma unroll
        for (int r = 0; r < 4; ++r) {
            #pragma unroll
            for (int off = 1; off < 16; off <<= 1) {
                vsr[r] += __shfl_xor(vsr[r], off, 64);
                vdr[r] += __shfl_xor(vdr[r], off, 64);
            }
            const int node = n0 + 16 * w + q * 4 + r;
            if (c == 0 && node < N) {
                a_s2[node] = vsr[r];
                a_d2[node] = vdr[r];
            }
        }
    }
    __syncthreads();
    #pragma unroll
    for (int nt = 0; nt < 4; ++nt)
        #pragma unroll
        for (int r = 0; r < 4; ++r)
            lds[(16 * w + q * 4 + r) * 72 + nt * 16 + c] = (short)pk(acc2[nt][r]);
    __syncthreads();
    for (int i = t; i < 64 * 8; i += 256) {
        const int r = i >> 3, ch = (i & 7) * 8;
        const int node = n0 + r;
        if (node < N)
            *(short8*)&h2b[(size_t)node * OUT_DIM + ch] =
                *(const short8*)&lds[r * 72 + ch];
    }
}

// ====== Layer-2 aggregate: 1 wave/node, lane = 2 ch; LDS-staged weights =====
__global__ __launch_bounds__(256) void agg2_k(
    const int* __restrict__ rowptr, const int* __restrict__ col,
    const float* __restrict__ a_s2, const float* __restrict__ a_d2,
    const unsigned short* __restrict__ h2b, const float* __restrict__ b2,
    float* __restrict__ zout, int N)
{
    __shared__ int2 swS[4][64];
    const int t = threadIdx.x, w = t >> 6, l = t & 63;
    const int n = blockIdx.x * 4 + w;
    if (n >= N) return;
    const int beg = rowptr[n], end = rowptr[n + 1];
    const float dn = a_d2[n];
    const int half = l >> 5, c2 = l & 31;     // lane owns ch 2*c2, 2*c2+1
    f32x2 acc = {0.f, 0.f};
    float wsum = 0.f;
    const unsigned short* h2l = h2b + 2 * c2;
    for (int t0 = beg; t0 < end; t0 += 64) {
        const int m = min(64, end - t0);
        const int p = t0 + l;
        int sc = 0; float wv = 0.f;
        if (p < end) {
            sc = col[p];
            wv = expc(lrelu(a_s2[sc] + dn));
            wsum += wv;
        }
        swS[w][l] = make_int2(sc, __float_as_int(wv));
        __threadfence_block();           // within-wave LDS write->read order
        const int pairs = (m + 1) >> 1;
        for (int j0 = 0; j0 < pairs; j0 += 8) {
            int2 sv[8];
            #pragma unroll
            for (int u = 0; u < 8; ++u)
                sv[u] = swS[w][2 * (j0 + u) + half];
            unsigned int hv[8];
            #pragma unroll
            for (int u = 0; u < 8; ++u)
                hv[u] = *(const unsigned int*)(h2l + (size_t)sv[u].x * OUT_DIM);
            #pragma unroll
            for (int u = 0; u < 8; ++u) {
                union { int2 i; f32x2 f; } cv; cv.i = sv[u];
                pkfma_hi(acc, bf2up(hv[u]), cv.f);
            }
        }
    }
    float a0 = acc[0], a1 = acc[1];
    a0 += __shfl_xor(a0, 32, 64);
    a1 += __shfl_xor(a1, 32, 64);
    #pragma unroll
    for (int off = 1; off < 64; off <<= 1) wsum += __shfl_xor(wsum, off, 64);
    const float inv = 1.f / (wsum + 1e-16f);
    float z0 = a0 * inv + b2[2 * c2];
    float z1 = a1 * inv + b2[2 * c2 + 1];
    float sq = z0 * z0 + z1 * z1;
    #pragma unroll
    for (int off = 1; off < 32; off <<= 1) sq += __shfl_xor(sq, off, 64);
    const float rn = 1.f / fmaxf(sqrtf(sq), 1e-12f);
    if (l < 32) {
        float2 o; o.x = z0 * rn; o.y = z1 * rn;
        *(float2*)&zout[(size_t)n * OUT_DIM + 2 * c2] = o;
    }
}

// ================= Decoder: x_hat = elu(z@dW1+db1)@dW2+db2 =================
__global__ __launch_bounds__(256) void dec_k(
    const float* __restrict__ z,
    const float* __restrict__ dW1, const float* __restrict__ db1,
    const float* __restrict__ dW2, const float* __restrict__ db2,
    float* __restrict__ xhat, int N)
{
    __shared__ float zs[32 * 64];
    __shared__ float ts[32 * 64];
    const int t = threadIdx.x;
    const int n0 = blockIdx.x * 32;
    for (int i = t; i < 32 * 64; i += 256) {
        const int nb_l = i >> 6, k = i & 63;
        const int n = min(n0 + nb_l, N - 1);
        zs[(nb_l >> 3) * 512 + k * 8 + (nb_l & 7)] = z[(size_t)n * OUT_DIM + k];
    }
    __syncthreads();
    const int w = t >> 6, l = t & 63;
    const float* zw = zs + w * 512;
    float* tw = ts + w * 512;
    float acc[8] = {0.f, 0.f, 0.f, 0.f, 0.f, 0.f, 0.f, 0.f};
    #pragma unroll 4
    for (int k = 0; k < 64; ++k) {
        const float wv = dW1[k * HID + l];
        const float4 xa = *(const float4*)&zw[k * 8];
        const float4 xb = *(const float4*)&zw[k * 8 + 4];
        acc[0] += xa.x * wv; acc[1] += xa.y * wv;
        acc[2] += xa.z * wv; acc[3] += xa.w * wv;
        acc[4] += xb.x * wv; acc[5] += xb.y * wv;
        acc[6] += xb.z * wv; acc[7] += xb.w * wv;
    }
    const float bb = db1[l];
    #pragma unroll
    for (int nb = 0; nb < 8; ++nb) tw[l * 8 + nb] = elu1(acc[nb] + bb);
    __syncthreads();
    float a0[8] = {0.f, 0.f, 0.f, 0.f, 0.f, 0.f, 0.f, 0.f};
    float a1[8] = {0.f, 0.f, 0.f, 0.f, 0.f, 0.f, 0.f, 0.f};
    #pragma unroll 2
    for (int k = 0; k < 64; ++k) {
        const float w0 = dW2[k * IN_DIM + l];
        const float w1 = dW2[k * IN_DIM + 64 + l];
        const float4 xa = *(const float4*)&tw[k * 8];
        const float4 xb = *(const float4*)&tw[k * 8 + 4];
        const float xv[8] = {xa.x, xa.y, xa.z, xa.w, xb.x, xb.y, xb.z, xb.w};
        #pragma unroll
        for (int nb = 0; nb < 8; ++nb) {
            a0[nb] += xv[nb] * w0;
            a1[nb] += xv[nb] * w1;
        }
    }
    const float bb0 = db2[l], bb1 = db2[64 + l];
    #pragma unroll
    for (int nb = 0; nb < 8; ++nb) {
        const int n = n0 + w * 8 + nb;
        if (n >= N) break;
        xhat[(size_t)n * IN_DIM + l]      = a0[nb] + bb0;
        xhat[(size_t)n * IN_DIM + 64 + l] = a1[nb] + bb1;
    }
}

extern "C" void kernel_launch(void* const* d_in, const int* in_sizes, int n_in,
                              void* d_out, int out_size, void* d_ws, size_t ws_size,
                              hipStream_t stream)
{
    const float* x   = (const float*)d_in[0];
    const int*   ei  = (const int*)d_in[1];
    const float* W1  = (const float*)d_in[2];
    const float* as1 = (const float*)d_in[3];
    const float* ad1 = (const float*)d_in[4];
    const float* b1  = (const float*)d_in[5];
    const float* W2  = (const float*)d_in[6];
    const float* as2 = (const float*)d_in[7];
    const float* ad2 = (const float*)d_in[8];
    const float* b2  = (const float*)d_in[9];
    const float* dW1 = (const float*)d_in[10];
    const float* db1 = (const float*)d_in[11];
    const float* dW2 = (const float*)d_in[12];
    const float* db2 = (const float*)d_in[13];

    const int N    = in_sizes[0] / IN_DIM;
    const int E    = in_sizes[1] / 2;
    const int Etot = E + N;
    const int NR   = (N + 255) >> 8;             // node ranges (<= 256)

    // fixed-size region first (keeps every u16 array 16B-aligned for any N)
    unsigned short* W1f = (unsigned short*)d_ws;           // 32768 u16
    unsigned short* W2f = W1f + 32768;                     // 16384 u16
    float* u_s = (float*)(W2f + 16384);                    // 512 f32
    float* u_d = u_s + 512;                                // 512 f32
    unsigned short* xagg = (unsigned short*)(u_d + 512);   // N*512 u16
    unsigned short* xb   = xagg + (size_t)N * 512;         // N*128 u16
    unsigned short* h2b  = xb   + (size_t)N * IN_DIM;      // N*64  u16
    float* a_s1 = (float*)(h2b + (size_t)N * OUT_DIM);     // N*4
    float* a_d1 = a_s1 + (size_t)N * HEADS;                // N*4
    float* a_s2 = a_d1 + (size_t)N * HEADS;                // N
    float* a_d2 = a_s2 + (size_t)N;                        // N
    int* rowptr = (int*)(a_d2 + (size_t)N);                // N+1
    int* col    = rowptr + (N + 1);                        // Etot
    unsigned int* eb = (unsigned int*)(col + Etot);        // Etot
    int* rtot   = (int*)(eb + Etot);                       // 256
    int* rbase  = rtot + 256;                              // 256
    int* rcur   = rbase + 256;                             // 256

    const size_t needed = (size_t)N * 1452 + (size_t)Etot * 8 + 105512;
    if (ws_size < needed || NR > 256) return;    // loud failure signature

    hipMemsetAsync(rtot, 0, 256 * sizeof(int), stream);

    const int mblk  = (N + 63) / 64;
    const int nblk4 = (N + 3) / 4;
    const int CA    = (Etot + 2047) / 2048;      // edge chunks (~416)
    w1f_k      <<<25, 256, 0, stream>>>(W1, W2, as1, ad1, W1f, W2f, u_s, u_d);
    xprep_cnt_k<<<CA + nblk4, 256, 0, stream>>>(x, u_s, u_d, xb, a_s1, a_d1,
                                                N, ei, E, Etot, rtot, CA, NR);
    scanR_k    <<<1, 256, 0, stream>>>(rtot, rbase, rcur, rowptr, NR, N, Etot);
    scat_k     <<<CA, 256, 0, stream>>>(ei, E, Etot, rcur, eb, CA, NR);
    rsort_k    <<<NR, 256, 0, stream>>>(eb, rtot, rbase, rowptr, col, N);
    agg1x_k    <<<nblk4, 256, 0, stream>>>(rowptr, col, a_s1, a_d1, xb, xagg, N);
    gemm12_k   <<<mblk, 256, 0, stream>>>(xagg, W1f, b1, W2f, as2, ad2, h2b,
                                          a_s2, a_d2, N);
    agg2_k     <<<nblk4, 256, 0, stream>>>(rowptr, col, a_s2, a_d2, h2b, b2,
                                           (float*)d_out, N);
    dec_k      <<<(N + 31) / 32, 256, 0, stream>>>((const float*)d_out, dW1,
                                                   db1, dW2, db2,
                                                   (float*)d_out + (size_t)N * OUT_DIM, N);
}